// Round 2
// 1314.666 us; speedup vs baseline: 1.7273x; 1.7273x over previous
//
#include <hip/hip_runtime.h>
#include <hip/hip_fp16.h>

// Problem dims
constexpr int kT = 512, kB = 32, kD = 512, kH = 256, kA1 = 16, kA2 = 128;

typedef _Float16 h2_t __attribute__((ext_vector_type(2)));
typedef _Float16 h8_t __attribute__((ext_vector_type(8)));

#if defined(__has_builtin)
#if __has_builtin(__builtin_amdgcn_fdot2)
#define HAVE_FDOT2 1
#endif
#endif

__device__ __forceinline__ float fast_tanh(float x) {
    // tanh(x) = 1 - 2/(exp(2x)+1); exp overflow -> inf -> 2/inf=0 -> 1 (correct)
    float e = __expf(2.0f * x);
    return 1.0f - 2.0f / (e + 1.0f);
}
__device__ __forceinline__ float fast_sig(float x) {
    return 1.0f / (1.0f + __expf(-x));
}

__device__ __forceinline__ float dot_pair(h2_t w, h2_t h, float acc) {
#if defined(HAVE_FDOT2)
    return __builtin_amdgcn_fdot2(w, h, acc, false);
#else
    acc = fmaf((float)w[0], (float)h[0], acc);
    return fmaf((float)w[1], (float)h[1], acc);
#endif
}

// ---------------- Kernel 1: attention over feature axis D -> seq (T,B) -------
__global__ __launch_bounds__(256) void att1_kernel(
    const float* __restrict__ x, const float* __restrict__ W1,
    const float* __restrict__ b1, const float* __restrict__ u1,
    float* __restrict__ seq) {
    int blk = blockIdx.x;                 // t*32 + b ; x offset = blk*kD
    int tid = threadIdx.x;
    const float* xp = x + (size_t)blk * kD;
    float x0 = xp[tid], x1 = xp[tid + 256];
    float s0 = 0.f, s1 = 0.f;
#pragma unroll
    for (int a = 0; a < kA1; ++a) {
        float w = W1[a], bb = b1[a], uu = u1[a];
        s0 += fast_tanh(fmaf(x0, w, bb)) * uu;
        s1 += fast_tanh(fmaf(x1, w, bb)) * uu;
    }
    float e0 = __expf(s0), e1 = __expf(s1);
    float se = e0 + e1;
    float sxe = fmaf(x0, e0, x1 * e1);
#pragma unroll
    for (int m = 32; m; m >>= 1) {
        se  += __shfl_xor(se,  m, 64);
        sxe += __shfl_xor(sxe, m, 64);
    }
    __shared__ float r_se[4], r_sxe[4];
    int wave = tid >> 6, lane = tid & 63;
    if (lane == 0) { r_se[wave] = se; r_sxe[wave] = sxe; }
    __syncthreads();
    if (tid == 0) {
        float S = r_se[0] + r_se[1] + r_se[2] + r_se[3];
        float X = r_sxe[0] + r_sxe[1] + r_sxe[2] + r_sxe[3];
        seq[blk] = X / S;
    }
}

// ------------- Kernel 1b: convert W_hh (4H,H) fp32 -> packed fp16 ------------
// Layout (half units): WQ[kk4*8192 + j*8 + q*2 + {0,1}] = W_hh[j][2*(4*kk4+q) + {0,1}]
// => as 16B vectors: W8[kk4*1024 + j] holds 8 consecutive k for row j.
__global__ __launch_bounds__(256) void wconv_kernel(
    const float* __restrict__ Whh, _Float16* __restrict__ WQ) {
    int idx = blockIdx.x * 256 + threadIdx.x;   // 0..131071 = j*128 + kk
    int j = idx >> 7, kk = idx & 127;
    int kk4 = kk >> 2, q = kk & 3;
    float a = Whh[j * kH + 2 * kk];
    float b = Whh[j * kH + 2 * kk + 1];
    _Float16* dst = WQ + ((size_t)kk4 * 8192 + j * 8 + q * 2);
    dst[0] = (_Float16)a;
    dst[1] = (_Float16)b;
}

// ---------------- Kernel 2: persistent per-batch LSTM ------------------------
// One workgroup (512 threads, 8 waves) per batch element. Thread j owns gate
// rows j and j+512 (PyTorch order: i=[0,H), f=[H,2H), g=[2H,3H), o=[3H,4H)
// => j<256 owns (i[j], g[j]); j>=256 owns (f[j-256], o[j-256])).
//
// Weight residency (the whole point): k in [0,192) of both rows lives in
// 192 VGPRs/thread (384 KB/block); k in [192,256) lives in a 128 KB LDS slab
// staged once. Zero per-step L2 traffic (was 512 KB/step -> L2-BW-bound).
// h is broadcast per-wave via v_readlane (2 fp16-pairs per lane), keeping the
// LDS port free for the weight-tail reads. Barriers are lgkmcnt-only (no
// vmcnt drain), so the hs global store floats across steps.
#define LSTM_BARRIER() asm volatile("s_waitcnt lgkmcnt(0)\n\ts_barrier" ::: "memory")

// h-pair broadcast: pair KK (h elements 2KK,2KK+1) via readlane. Lane select
// is uniform (SGPR) — no frontend-constant requirement, folds after unroll.
#define HPAIR(KK) __builtin_bit_cast(h2_t, (unsigned)__builtin_amdgcn_readlane( \
        ((KK) < 64) ? (int)hr0 : (int)hr1, (KK) & 63))

// 4 h-pairs (one h8_t weight vector) worth of fdot2, literal shuffle indices.
#define DOT4(W0, W1, KKB) do { \
    h2_t _hp0 = HPAIR((KKB) + 0); \
    acc0 = dot_pair(__builtin_shufflevector((W0), (W0), 0, 1), _hp0, acc0); \
    acc1 = dot_pair(__builtin_shufflevector((W1), (W1), 0, 1), _hp0, acc1); \
    h2_t _hp1 = HPAIR((KKB) + 1); \
    acc0 = dot_pair(__builtin_shufflevector((W0), (W0), 2, 3), _hp1, acc0); \
    acc1 = dot_pair(__builtin_shufflevector((W1), (W1), 2, 3), _hp1, acc1); \
    h2_t _hp2 = HPAIR((KKB) + 2); \
    acc0 = dot_pair(__builtin_shufflevector((W0), (W0), 4, 5), _hp2, acc0); \
    acc1 = dot_pair(__builtin_shufflevector((W1), (W1), 4, 5), _hp2, acc1); \
    h2_t _hp3 = HPAIR((KKB) + 3); \
    acc0 = dot_pair(__builtin_shufflevector((W0), (W0), 6, 7), _hp3, acc0); \
    acc1 = dot_pair(__builtin_shufflevector((W1), (W1), 6, 7), _hp3, acc1); \
} while (0)

__global__ __launch_bounds__(512, 2) void lstm_kernel(
    const float* __restrict__ seq, const _Float16* __restrict__ WQ,
    const float* __restrict__ W_ih, const float* __restrict__ b_ih,
    const float* __restrict__ b_hh, const float* __restrict__ h0,
    const float* __restrict__ c0, float* __restrict__ hs) {
    int b = blockIdx.x;
    int j = threadIdx.x;          // 0..511
    int lane = j & 63;

    __shared__ float seq_l[kT];                            // 2 KB
    __shared__ __align__(16) _Float16 wtail[8 * 1024 * 8]; // 128 KB: kk4=24..31
    __shared__ float fo[2][kH];                            // 2 KB (f and o gates)
    __shared__ __align__(8) _Float16 hl[kH];               // 512 B

    for (int t = j; t < kT; t += 512) seq_l[t] = seq[t * kB + b];

    const h8_t* W8 = (const h8_t*)WQ;
    h8_t* wt8 = (h8_t*)wtail;
    // stage LDS weight tail (once): slices kk4 = 24..31, all 1024 rows
    for (int idx = j; idx < 8 * 1024; idx += 512)
        wt8[idx] = W8[(24 + (idx >> 10)) * 1024 + (idx & 1023)];

    // register-resident weights: kk4 = 0..23 for rows j and j+512
    h8_t wr0[24], wr1[24];
#pragma unroll
    for (int kk4 = 0; kk4 < 24; ++kk4) {
        wr0[kk4] = W8[kk4 * 1024 + j];
        wr1[kk4] = W8[kk4 * 1024 + j + 512];
    }

    int r0 = j, r1 = j + 512;
    float wih0 = W_ih[r0], wih1 = W_ih[r1];
    float bias0 = b_ih[r0] + b_hh[r0];
    float bias1 = b_ih[r1] + b_hh[r1];
    float c = 0.f;
    if (j < kH) {
        c = c0[b * kH + j];
        hl[j] = (_Float16)h0[b * kH + j];
    }
    LSTM_BARRIER();

    const unsigned* hl32 = (const unsigned*)hl;   // 128 packed fp16-pairs
    unsigned hr0 = hl32[lane];                    // pairs 0..63   (lane l -> pair l)
    unsigned hr1 = hl32[lane + 64];               // pairs 64..127

#pragma unroll 1
    for (int t = 0; t < kT; ++t) {
        float st = seq_l[t];
        float acc0 = fmaf(st, wih0, bias0);
        float acc1 = fmaf(st, wih1, bias1);

        // k in [0,192): weights from VGPRs, h broadcast via readlane
#pragma unroll
        for (int kk4 = 0; kk4 < 24; ++kk4) {
            DOT4(wr0[kk4], wr1[kk4], kk4 * 4);
        }
        // k in [192,256): weights from the LDS slab (pairs 96..127 -> hr1 lanes 32..63)
#pragma unroll
        for (int q = 0; q < 8; ++q) {
            h8_t w0 = wt8[q * 1024 + j];
            h8_t w1 = wt8[q * 1024 + j + 512];
            DOT4(w0, w1, 96 + q * 4);
        }

        if (j >= kH) {            // publish f and o gates
            fo[0][j - kH] = acc0;
            fo[1][j - kH] = acc1;
        }
        LSTM_BARRIER();

        if (j < kH) {             // i,g in registers; f,o from LDS
            float ig = fast_sig(acc0);
            float gg = fast_tanh(acc1);
            float fg = fast_sig(fo[0][j]);
            float og = fast_sig(fo[1][j]);
            c = fmaf(fg, c, ig * gg);
            float h = og * fast_tanh(c);
            hs[(size_t)t * (kB * kH) + b * kH + j] = h;   // store floats, never drained
            hl[j] = (_Float16)h;
        }
        LSTM_BARRIER();

        hr0 = hl32[lane];
        hr1 = hl32[lane + 64];
    }
}

// ---------------- Kernel 3a: attention-2 scores e2 (T,B) ---------------------
// Block = (b, chunk of 16 t). 128 threads, thread a owns attention unit a.
__global__ __launch_bounds__(128) void att2a_kernel(
    const float* __restrict__ hs, const float* __restrict__ W2,
    const float* __restrict__ b2, const float* __restrict__ u2,
    float* __restrict__ a2w) {
    int b  = blockIdx.x & 31;
    int tc = blockIdx.x >> 5;   // 0..31
    int a  = threadIdx.x;       // 0..127
    __shared__ __align__(16) float hl[16][kH];
    __shared__ float red[16][2];
    int t0 = tc * 16;
    for (int tt = 0; tt < 16; ++tt) {
        const float* hp = hs + ((size_t)(t0 + tt) * kB + b) * kH;
        hl[tt][a]       = hp[a];
        hl[tt][a + 128] = hp[a + 128];
    }
    __syncthreads();
    float dot[16];
#pragma unroll
    for (int tt = 0; tt < 16; ++tt) dot[tt] = 0.f;
    for (int k = 0; k < kH; k += 4) {
        float w0 = W2[(k + 0) * kA2 + a];
        float w1 = W2[(k + 1) * kA2 + a];
        float w2 = W2[(k + 2) * kA2 + a];
        float w3 = W2[(k + 3) * kA2 + a];
#pragma unroll
        for (int tt = 0; tt < 16; ++tt) {
            float4 h4 = *(const float4*)&hl[tt][k];
            dot[tt] = fmaf(h4.x, w0, dot[tt]);
            dot[tt] = fmaf(h4.y, w1, dot[tt]);
            dot[tt] = fmaf(h4.z, w2, dot[tt]);
            dot[tt] = fmaf(h4.w, w3, dot[tt]);
        }
    }
    float bb = b2[a], uu = u2[a];
    int wave = a >> 6, lane = a & 63;
#pragma unroll
    for (int tt = 0; tt < 16; ++tt) {
        float v = fast_tanh(dot[tt] + bb) * uu;
#pragma unroll
        for (int m = 32; m; m >>= 1) v += __shfl_xor(v, m, 64);
        if (lane == 0) red[tt][wave] = v;
    }
    __syncthreads();
    if (a < 16) {
        float s = red[a][0] + red[a][1];
        a2w[(t0 + a) * kB + b] = __expf(s);
    }
}

// ---------------- Kernel 3b: weighted time-pool + linear head ----------------
__global__ __launch_bounds__(256) void att2b_kernel(
    const float* __restrict__ hs, const float* __restrict__ a2w,
    const float* __restrict__ Wl, const float* __restrict__ bl,
    float* __restrict__ out) {
    int b = blockIdx.x;
    int k = threadIdx.x;
    float acc = 0.f, den = 0.f;
    for (int t = 0; t < kT; ++t) {
        float e = a2w[t * kB + b];            // broadcast
        float h = hs[((size_t)t * kB + b) * kH + k];
        acc = fmaf(h, e, acc);
        den += e;
    }
    float v = (acc / den) * Wl[k];
#pragma unroll
    for (int m = 32; m; m >>= 1) v += __shfl_xor(v, m, 64);
    __shared__ float red[4];
    int wave = k >> 6, lane = k & 63;
    if (lane == 0) red[wave] = v;
    __syncthreads();
    if (k == 0) out[b] = red[0] + red[1] + red[2] + red[3] + bl[0];
}

extern "C" void kernel_launch(void* const* d_in, const int* in_sizes, int n_in,
                              void* d_out, int out_size, void* d_ws, size_t ws_size,
                              hipStream_t stream) {
    const float* inputs = (const float*)d_in[0];
    const float* W1   = (const float*)d_in[1];
    const float* b1   = (const float*)d_in[2];
    const float* u1   = (const float*)d_in[3];
    const float* W_ih = (const float*)d_in[4];
    const float* W_hh = (const float*)d_in[5];
    const float* b_ih = (const float*)d_in[6];
    const float* b_hh = (const float*)d_in[7];
    const float* h0   = (const float*)d_in[8];
    const float* c0   = (const float*)d_in[9];
    const float* W2   = (const float*)d_in[10];
    const float* b2   = (const float*)d_in[11];
    const float* u2   = (const float*)d_in[12];
    const float* Wl   = (const float*)d_in[13];
    const float* bl   = (const float*)d_in[14];
    float* out = (float*)d_out;

    char* ws = (char*)d_ws;
    float*    seq = (float*)(ws);                    // 64 KB  (T*B fp32)
    float*    a2w = (float*)(ws + (64 << 10));       // 64 KB  (T*B fp32)
    _Float16* WQ  = (_Float16*)(ws + (128 << 10));   // 512 KB (4H*H fp16, packed)
    float*    hs  = (float*)(ws + (1 << 20));        // 16 MB  (T*B*H fp32)

    att1_kernel <<<kT * kB, 256, 0, stream>>>(inputs, W1, b1, u1, seq);
    wconv_kernel<<<512, 256, 0, stream>>>(W_hh, WQ);
    lstm_kernel <<<kB, 512, 0, stream>>>(seq, WQ, W_ih, b_ih, b_hh, h0, c0, hs);
    att2a_kernel<<<1024, 128, 0, stream>>>(hs, W2, b2, u2, a2w);
    att2b_kernel<<<kB, 256, 0, stream>>>(hs, a2w, Wl, bl, out);
}